// Round 4
// baseline (7763.720 us; speedup 1.0000x reference)
//
#include <hip/hip_runtime.h>
#include <hip/hip_bf16.h>

#define B_ 16
#define S_ 256
#define E_ 512
#define H_ 1024
#define V_ 32000
#define SCAN_NB 32   // scan grid size

typedef __attribute__((ext_vector_type(8))) short short8;
typedef __attribute__((ext_vector_type(4))) float f32x4;
typedef __attribute__((ext_vector_type(4))) unsigned u32x4;

__device__ __forceinline__ unsigned short f2h(float f) {
  _Float16 h = (_Float16)f;
  return __builtin_bit_cast(unsigned short, h);
}

// ---------------- prep kernels ----------------

__global__ void k_init(unsigned* __restrict__ p, int n) {
  int i = blockIdx.x * 256 + threadIdx.x;
  if (i < n) p[i] = 0u;
}

__global__ void k_cast(const float* __restrict__ s, unsigned short* __restrict__ d, int n4) {
  int i = blockIdx.x * 256 + threadIdx.x;
  if (i >= n4) return;
  float4 v = ((const float4*)s)[i];
  ushort4 o;
  o.x = f2h(v.x); o.y = f2h(v.y); o.z = f2h(v.z); o.w = f2h(v.w);
  ((ushort4*)d)[i] = o;
}

// xe[m][k] = f16(emb[x[b,s]][k]), m = s*16 + b
__global__ void k_gather(const int* __restrict__ x, const float* __restrict__ emb,
                         unsigned short* __restrict__ xe) {
  int m = blockIdx.x;
  int s = m >> 4, b = m & 15;
  int tok = x[b * S_ + s];
  int k = threadIdx.x * 4;
  float4 v = *(const float4*)(emb + (size_t)tok * E_ + k);
  ushort4 o;
  o.x = f2h(v.x); o.y = f2h(v.y); o.z = f2h(v.z); o.w = f2h(v.w);
  *(ushort4*)(xe + (size_t)m * E_ + k) = o;
}

// ---------------- f16 MFMA GEMM:  C[m][n] = sum_k A[m,k]*W[n,k] + bias[n] ----------------

__global__ __launch_bounds__(256, 1) void k_gemm(
    const unsigned short* __restrict__ A,
    const unsigned short* __restrict__ W0, const unsigned short* __restrict__ W1,
    const unsigned short* __restrict__ W2,
    const float* __restrict__ b0, const float* __restrict__ b1, const float* __restrict__ b2,
    float* __restrict__ C, int K, int mtiles, int gshift, int permute, int ldc) {
  __shared__ unsigned short As[128][40];
  __shared__ unsigned short Bs[128][40];

  const int tid = threadIdx.x;
  const int mt = blockIdx.x % mtiles, nt = blockIdx.x / mtiles;
  const int m0 = mt * 128, n0 = nt * 128;
  const int wave = tid >> 6, lane = tid & 63;
  const int wm = (wave >> 1) * 64, wn = (wave & 1) * 64;
  const int lr = lane & 15, lk = (lane >> 4) * 8;
  const int ar = tid >> 2, as = (tid & 3) * 8;
  const unsigned kmask = (1u << gshift) - 1u;

  int j1 = n0 + ar, j2 = n0 + ar + 64;
  int g1 = j1 >> gshift, g2 = j2 >> gshift;
  const unsigned short* bp1 = (g1 == 0 ? W0 : (g1 == 1 ? W1 : W2)) + (size_t)(j1 & kmask) * K + as;
  const unsigned short* bp2 = (g2 == 0 ? W0 : (g2 == 1 ? W1 : W2)) + (size_t)(j2 & kmask) * K + as;
  const unsigned short* ap1 = A + (size_t)(m0 + ar) * K + as;
  const unsigned short* ap2 = A + (size_t)(m0 + ar + 64) * K + as;

  const f32x4 zero4 = {0.f, 0.f, 0.f, 0.f};
  f32x4 acc[4][4];
#pragma unroll
  for (int i = 0; i < 4; ++i)
#pragma unroll
    for (int j = 0; j < 4; ++j) acc[i][j] = zero4;

  for (int k0 = 0; k0 < K; k0 += 32) {
    int4 va1 = *(const int4*)(ap1 + k0);
    int4 va2 = *(const int4*)(ap2 + k0);
    int4 vb1 = *(const int4*)(bp1 + k0);
    int4 vb2 = *(const int4*)(bp2 + k0);
    __syncthreads();
    *(int4*)&As[ar][as] = va1;
    *(int4*)&As[ar + 64][as] = va2;
    *(int4*)&Bs[ar][as] = vb1;
    *(int4*)&Bs[ar + 64][as] = vb2;
    __syncthreads();
    short8 af[4], bf[4];
#pragma unroll
    for (int i = 0; i < 4; ++i) af[i] = *(const short8*)&As[wm + i * 16 + lr][lk];
#pragma unroll
    for (int j = 0; j < 4; ++j) bf[j] = *(const short8*)&Bs[wn + j * 16 + lr][lk];
#pragma unroll
    for (int i = 0; i < 4; ++i)
#pragma unroll
      for (int j = 0; j < 4; ++j)
        acc[i][j] = __builtin_amdgcn_mfma_f32_16x16x32_f16(af[i], bf[j], acc[i][j], 0, 0, 0);
  }

#pragma unroll
  for (int j = 0; j < 4; ++j) {
    int col = n0 + wn + j * 16 + lr;
    int g = col >> gshift;
    const float* bp = (g == 0 ? b0 : (g == 1 ? b1 : b2));
    float bv = bp[col & kmask];
#pragma unroll
    for (int i = 0; i < 4; ++i) {
      int rbase = m0 + wm + i * 16 + (lane >> 4) * 4;
#pragma unroll
      for (int r = 0; r < 4; ++r) {
        int mrow = rbase + r;
        size_t off;
        if (permute) {
          int s = mrow >> 4, b = mrow & 15;
          off = ((size_t)(b * S_ + s)) * ldc + col;
        } else {
          off = (size_t)mrow * ldc + col;
        }
        C[off] = acc[i][j][r] + bv;
      }
    }
  }
}

// ---------------- tagged-packet comm primitives ----------------
// Packet (16B): { f16 d0,d1,d2,d3, u32 tag, u32 pad }. One dwordx4 = one memory
// transaction -> tag and data atomically consistent. sc0 sc1 = bypass L1/L2,
// LLC-coherent, no cache invalidations.

__device__ __forceinline__ void llc_store16(u32x4* p, u32x4 v) {
  asm volatile("global_store_dwordx4 %0, %1, off sc0 sc1" :: "v"(p), "v"(v) : "memory");
}

// Spin until all 32 packets this lane needs carry `tag`; data stays in ch[][].
__device__ __forceinline__ void spin_load(const u32x4* __restrict__ base, unsigned tag,
                                          u32x4 (&ch)[16][2]) {
  while (true) {
#pragma unroll
    for (int kk = 0; kk < 16; ++kk) {
      asm volatile("global_load_dwordx4 %0, %1, off sc0 sc1"
                   : "=v"(ch[kk][0]) : "v"(base + kk * 8));
      asm volatile("global_load_dwordx4 %0, %1, off sc0 sc1"
                   : "=v"(ch[kk][1]) : "v"(base + kk * 8 + 1));
    }
    asm volatile("s_waitcnt vmcnt(0)" ::: "memory");
    __builtin_amdgcn_sched_barrier(0);
    unsigned x = 0;
#pragma unroll
    for (int kk = 0; kk < 16; ++kk)
      x |= (ch[kk][0].z ^ tag) | (ch[kk][1].z ^ tag);
    if (__all(x == 0)) return;
    __builtin_amdgcn_s_sleep(1);
  }
}

// ---------------- persistent MFMA GRU scan (flag-free) ----------------
// 32 blocks x 256 threads; wave = (tile in {0,1}, kh in {0,1}); block owns
// features [32*blk, 32*blk+32). Chunk index: b*256 + blk*8 + c (c = feat/4 in block).
// Epochs: rh(t) tag = 2t, h(t) tag = 2t+1.
__global__ __launch_bounds__(256, 1) void k_scan(
    const float* __restrict__ Gx,   // [S][B][3H] f32 (z|r|n)
    const float* __restrict__ Whz, const float* __restrict__ Whr, const float* __restrict__ Whn,
    unsigned short* __restrict__ Hseq,  // [S][B][H] f16 clean (GEMM input)
    u32x4* __restrict__ hchk,           // [16*32*8] h packets
    u32x4* __restrict__ rchk,           // [16*32*8] rh packets
    float* __restrict__ hfin) {         // [B][H] f32 (d_out tail)
  const int tid = threadIdx.x, lane = tid & 63, wave = tid >> 6;
  const int tile = wave >> 1, kh = wave & 1;
  const bool leader = (kh == 0);
  const int j0 = blockIdx.x * 32 + tile * 16;
  const int lj = lane & 15, lq = lane >> 4;
  const int kb = kh * 512;
  const int bq = lq * 4;

  __shared__ __align__(16) float comb[2][2][64][4];
  __shared__ __align__(16) unsigned short stage_r[16][32];
  __shared__ __align__(16) unsigned short stage_h[16][32];

  // ---- preload weights as B-fragments: lane holds W[j0+lj][kb+kk*32+lq*8 ..+8] ----
  short8 wz[16], wr[16], wn[16];
  {
    const size_t row = (size_t)(j0 + lj) * H_;
#pragma unroll
    for (int kk = 0; kk < 16; ++kk) {
      int col = kb + kk * 32 + lq * 8;
      const float* pz = Whz + row + col;
      const float* pr = Whr + row + col;
      const float* pn = Whn + row + col;
      short8 a, b, c;
#pragma unroll
      for (int e = 0; e < 8; ++e) {
        a[e] = (short)f2h(pz[e]);
        b[e] = (short)f2h(pr[e]);
        c[e] = (short)f2h(pn[e]);
      }
      wz[kk] = a; wr[kk] = b; wn[kk] = c;
    }
  }

  // consumer packet base for this lane: b=lj, blk=kh*16+kk, c=lq*2
  const unsigned cbase = (unsigned)lj * 256 + (unsigned)kh * 128 + (unsigned)lq * 2;
  const u32x4* hbase = hchk + cbase;
  const u32x4* rbase = rchk + cbase;

  float hold[4] = {0.f, 0.f, 0.f, 0.f};
  float zv[4] = {0.f, 0.f, 0.f, 0.f};
  const f32x4 zero4 = {0.f, 0.f, 0.f, 0.f};

  for (int t = 0; t < S_; ++t) {
    const float* gxt = Gx + (size_t)t * (B_ * 3 * H_);
    float gz[4], gr[4], gn[4];
    if (leader) {
#pragma unroll
      for (int r = 0; r < 4; ++r) {
        const float* gb = gxt + (size_t)(bq + r) * (3 * H_) + j0 + lj;
        gz[r] = gb[0]; gr[r] = gb[H_]; gn[r] = gb[2 * H_];
      }
    }

    // ---------- phase A: z, r ----------
    f32x4 zacc = zero4, racc = zero4;
    if (t > 0) {
      u32x4 ch[16][2];
      spin_load(hbase, (unsigned)(2 * t - 1), ch);
#pragma unroll
      for (int kk = 0; kk < 16; ++kk) {
        u32x4 fv = {ch[kk][0].x, ch[kk][0].y, ch[kk][1].x, ch[kk][1].y};
        short8 af = __builtin_bit_cast(short8, fv);
        zacc = __builtin_amdgcn_mfma_f32_16x16x32_f16(af, wz[kk], zacc, 0, 0, 0);
        racc = __builtin_amdgcn_mfma_f32_16x16x32_f16(af, wr[kk], racc, 0, 0, 0);
      }
      if (!leader) {
        *(f32x4*)&comb[tile][0][lane][0] = zacc;
        *(f32x4*)&comb[tile][1][lane][0] = racc;
      }
      __syncthreads();
      if (leader) {
        zacc += *(const f32x4*)&comb[tile][0][lane][0];
        racc += *(const f32x4*)&comb[tile][1][lane][0];
      }
    }
    if (leader) {
#pragma unroll
      for (int r = 0; r < 4; ++r) {
        zv[r] = 1.f / (1.f + __expf(-(gz[r] + zacc[r])));
        float rv = 1.f / (1.f + __expf(-(gr[r] + racc[r])));
        stage_r[bq + r][tile * 16 + lj] = f2h(rv * hold[r]);
      }
    }
    if (t > 0) {
      __syncthreads();
      if (tid < 128) {  // assemble + publish rh packets (fire-and-forget)
        const int b = tid >> 3, c = tid & 7;
        unsigned lo = (unsigned)stage_r[b][c * 4]     | ((unsigned)stage_r[b][c * 4 + 1] << 16);
        unsigned hi = (unsigned)stage_r[b][c * 4 + 2] | ((unsigned)stage_r[b][c * 4 + 3] << 16);
        u32x4 pkt = {lo, hi, (unsigned)(2 * t), 0u};
        llc_store16(rchk + (unsigned)b * 256 + (unsigned)blockIdx.x * 8 + c, pkt);
      }
    }

    // ---------- phase B: n, h update ----------
    f32x4 nacc = zero4;
    if (t > 0) {
      u32x4 ch[16][2];
      spin_load(rbase, (unsigned)(2 * t), ch);
#pragma unroll
      for (int kk = 0; kk < 16; ++kk) {
        u32x4 fv = {ch[kk][0].x, ch[kk][0].y, ch[kk][1].x, ch[kk][1].y};
        short8 af = __builtin_bit_cast(short8, fv);
        nacc = __builtin_amdgcn_mfma_f32_16x16x32_f16(af, wn[kk], nacc, 0, 0, 0);
      }
      if (!leader) *(f32x4*)&comb[tile][0][lane][0] = nacc;
      __syncthreads();
      if (leader) nacc += *(const f32x4*)&comb[tile][0][lane][0];
    }
    if (leader) {
#pragma unroll
      for (int r = 0; r < 4; ++r) {
        float nv = tanhf(gn[r] + nacc[r]);
        float hn = (1.f - zv[r]) * nv + zv[r] * hold[r];
        hold[r] = hn;
        stage_h[bq + r][tile * 16 + lj] = f2h(hn);
        if (t == S_ - 1) hfin[(size_t)(bq + r) * H_ + j0 + lj] = hn;
      }
    }
    __syncthreads();
    if (tid < 128) {  // publish h packets
      const int b = tid >> 3, c = tid & 7;
      unsigned lo = (unsigned)stage_h[b][c * 4]     | ((unsigned)stage_h[b][c * 4 + 1] << 16);
      unsigned hi = (unsigned)stage_h[b][c * 4 + 2] | ((unsigned)stage_h[b][c * 4 + 3] << 16);
      u32x4 pkt = {lo, hi, (unsigned)(2 * t + 1), 0u};
      llc_store16(hchk + (unsigned)b * 256 + (unsigned)blockIdx.x * 8 + c, pkt);
    }
    if (tid < 64) {  // clean Hseq row for the downstream GEMMs
      const int b = tid >> 2, g = tid & 3;
      u32x4 v = *(const u32x4*)&stage_h[b][g * 8];
      *(u32x4*)(Hseq + (size_t)t * (B_ * H_) + (size_t)b * H_ + blockIdx.x * 32 + g * 8) = v;
    }
  }
}

// ---------------- host ----------------

extern "C" void kernel_launch(void* const* d_in, const int* in_sizes, int n_in,
                              void* d_out, int out_size, void* d_ws, size_t ws_size,
                              hipStream_t stream) {
  const int*   x    = (const int*)d_in[0];
  const float* emb  = (const float*)d_in[1];
  const float* wxz0 = (const float*)d_in[2];
  const float* bxz0 = (const float*)d_in[3];
  const float* whz0 = (const float*)d_in[4];
  const float* wxr0 = (const float*)d_in[5];
  const float* bxr0 = (const float*)d_in[6];
  const float* whr0 = (const float*)d_in[7];
  const float* wxn0 = (const float*)d_in[8];
  const float* bxn0 = (const float*)d_in[9];
  const float* whn0 = (const float*)d_in[10];
  const float* wxz1 = (const float*)d_in[11];
  const float* bxz1 = (const float*)d_in[12];
  const float* whz1 = (const float*)d_in[13];
  const float* wxr1 = (const float*)d_in[14];
  const float* bxr1 = (const float*)d_in[15];
  const float* whr1 = (const float*)d_in[16];
  const float* wxn1 = (const float*)d_in[17];
  const float* bxn1 = (const float*)d_in[18];
  const float* whn1 = (const float*)d_in[19];
  const float* fcw  = (const float*)d_in[20];
  const float* fcb  = (const float*)d_in[21];
  float* out = (float*)d_out;

  char* w = (char*)d_ws;
  size_t off = 0;
  auto alloc = [&](size_t bytes) {
    void* p = w + off;
    off += (bytes + 255) & ~(size_t)255;
    return p;
  };
  unsigned short* xe   = (unsigned short*)alloc((size_t)4096 * E_ * 2);
  unsigned short* wz0b = (unsigned short*)alloc((size_t)H_ * E_ * 2);
  unsigned short* wr0b = (unsigned short*)alloc((size_t)H_ * E_ * 2);
  unsigned short* wn0b = (unsigned short*)alloc((size_t)H_ * E_ * 2);
  unsigned short* wz1b = (unsigned short*)alloc((size_t)H_ * H_ * 2);
  unsigned short* wr1b = (unsigned short*)alloc((size_t)H_ * H_ * 2);
  unsigned short* wn1b = (unsigned short*)alloc((size_t)H_ * H_ * 2);
  unsigned short* fcwb = (unsigned short*)alloc((size_t)V_ * H_ * 2);
  float* Gx = (float*)alloc((size_t)4096 * 3 * H_ * 4);
  unsigned short* Hs0 = (unsigned short*)alloc((size_t)4096 * H_ * 2);
  unsigned short* Hs1 = (unsigned short*)alloc((size_t)4096 * H_ * 2);
  // chunk buffers (contiguous; zeroed at launch start): 4 x 64 KB
  u32x4* hchk0 = (u32x4*)alloc((size_t)B_ * 32 * 8 * 16);
  u32x4* rchk0 = (u32x4*)alloc((size_t)B_ * 32 * 8 * 16);
  u32x4* hchk1 = (u32x4*)alloc((size_t)B_ * 32 * 8 * 16);
  u32x4* rchk1 = (u32x4*)alloc((size_t)B_ * 32 * 8 * 16);

  float* h0f = out + (size_t)B_ * S_ * V_;
  float* h1f = h0f + (size_t)B_ * H_;

  // zero all 4 chunk buffers (kills stale tags from garbage / prior replays)
  {
    int nz = B_ * 32 * 8 * 4 * 4;  // u32 count of 4 buffers
    k_init<<<(nz + 255) / 256, 256, 0, stream>>>((unsigned*)hchk0, nz);
  }

  // prep: gather + casts (f16)
  k_gather<<<4096, 128, 0, stream>>>(x, emb, xe);
  k_cast<<<(H_ * E_ / 4 + 255) / 256, 256, 0, stream>>>(wxz0, wz0b, H_ * E_ / 4);
  k_cast<<<(H_ * E_ / 4 + 255) / 256, 256, 0, stream>>>(wxr0, wr0b, H_ * E_ / 4);
  k_cast<<<(H_ * E_ / 4 + 255) / 256, 256, 0, stream>>>(wxn0, wn0b, H_ * E_ / 4);
  k_cast<<<(H_ * H_ / 4 + 255) / 256, 256, 0, stream>>>(wxz1, wz1b, H_ * H_ / 4);
  k_cast<<<(H_ * H_ / 4 + 255) / 256, 256, 0, stream>>>(wxr1, wr1b, H_ * H_ / 4);
  k_cast<<<(H_ * H_ / 4 + 255) / 256, 256, 0, stream>>>(wxn1, wn1b, H_ * H_ / 4);
  k_cast<<<(V_ * H_ / 4 + 255) / 256, 256, 0, stream>>>(fcw, fcwb, V_ * H_ / 4);

  // Gx0 = xe @ Wx0^T + b  (M=4096, N=3072, K=512)
  k_gemm<<<32 * 24, 256, 0, stream>>>(xe, wz0b, wr0b, wn0b, bxz0, bxr0, bxn0,
                                      Gx, E_, 32, 10, 0, 3 * H_);
  // layer-0 scan
  k_scan<<<SCAN_NB, 256, 0, stream>>>(Gx, whz0, whr0, whn0, Hs0, hchk0, rchk0, h0f);
  // Gx1 = Hs0 @ Wx1^T + b  (K=1024)
  k_gemm<<<32 * 24, 256, 0, stream>>>(Hs0, wz1b, wr1b, wn1b, bxz1, bxr1, bxn1,
                                      Gx, H_, 32, 10, 0, 3 * H_);
  // layer-1 scan
  k_scan<<<SCAN_NB, 256, 0, stream>>>(Gx, whz1, whr1, whn1, Hs1, hchk1, rchk1, h1f);
  // out = Hs1 @ fcw^T + fcb  (M=4096, N=32000, K=1024), permuted to [B][S][V]
  k_gemm<<<32 * 250, 256, 0, stream>>>(Hs1, fcwb, fcwb, fcwb, fcb, fcb, fcb,
                                       out, H_, 32, 30, 1, V_);

  (void)in_sizes; (void)n_in; (void)out_size; (void)ws_size;
}

// Round 5
// 3856.886 us; speedup vs baseline: 2.0130x; 2.0130x over previous
//
#include <hip/hip_runtime.h>
#include <hip/hip_bf16.h>

#define B_ 16
#define S_ 256
#define E_ 512
#define H_ 1024
#define V_ 32000

typedef __attribute__((ext_vector_type(8))) short short8;
typedef __attribute__((ext_vector_type(4))) float f32x4;
typedef __attribute__((ext_vector_type(4))) unsigned u32x4;

__device__ __forceinline__ unsigned short f2h(float f) {
  _Float16 h = (_Float16)f;
  return __builtin_bit_cast(unsigned short, h);
}

// ---------------- prep kernels ----------------

__global__ void k_init(unsigned* __restrict__ p, int n) {
  int i = blockIdx.x * 256 + threadIdx.x;
  if (i < n) p[i] = 0u;
}

__global__ void k_cast(const float* __restrict__ s, unsigned short* __restrict__ d, int n4) {
  int i = blockIdx.x * 256 + threadIdx.x;
  if (i >= n4) return;
  float4 v = ((const float4*)s)[i];
  ushort4 o;
  o.x = f2h(v.x); o.y = f2h(v.y); o.z = f2h(v.z); o.w = f2h(v.w);
  ((ushort4*)d)[i] = o;
}

// xe[m][k] = f16(emb[x[b,s]][k]), m = s*16 + b
__global__ void k_gather(const int* __restrict__ x, const float* __restrict__ emb,
                         unsigned short* __restrict__ xe) {
  int m = blockIdx.x;
  int s = m >> 4, b = m & 15;
  int tok = x[b * S_ + s];
  int k = threadIdx.x * 4;
  float4 v = *(const float4*)(emb + (size_t)tok * E_ + k);
  ushort4 o;
  o.x = f2h(v.x); o.y = f2h(v.y); o.z = f2h(v.z); o.w = f2h(v.w);
  *(ushort4*)(xe + (size_t)m * E_ + k) = o;
}

// ---------------- f16 MFMA GEMM:  C[m][n] = sum_k A[m,k]*W[n,k] + bias[n] ----------------

__global__ __launch_bounds__(256, 1) void k_gemm(
    const unsigned short* __restrict__ A,
    const unsigned short* __restrict__ W0, const unsigned short* __restrict__ W1,
    const unsigned short* __restrict__ W2,
    const float* __restrict__ b0, const float* __restrict__ b1, const float* __restrict__ b2,
    float* __restrict__ C, int K, int mtiles, int gshift, int permute, int ldc) {
  __shared__ unsigned short As[128][40];
  __shared__ unsigned short Bs[128][40];

  const int tid = threadIdx.x;
  const int mt = blockIdx.x % mtiles, nt = blockIdx.x / mtiles;
  const int m0 = mt * 128, n0 = nt * 128;
  const int wave = tid >> 6, lane = tid & 63;
  const int wm = (wave >> 1) * 64, wn = (wave & 1) * 64;
  const int lr = lane & 15, lk = (lane >> 4) * 8;
  const int ar = tid >> 2, as = (tid & 3) * 8;
  const unsigned kmask = (1u << gshift) - 1u;

  int j1 = n0 + ar, j2 = n0 + ar + 64;
  int g1 = j1 >> gshift, g2 = j2 >> gshift;
  const unsigned short* bp1 = (g1 == 0 ? W0 : (g1 == 1 ? W1 : W2)) + (size_t)(j1 & kmask) * K + as;
  const unsigned short* bp2 = (g2 == 0 ? W0 : (g2 == 1 ? W1 : W2)) + (size_t)(j2 & kmask) * K + as;
  const unsigned short* ap1 = A + (size_t)(m0 + ar) * K + as;
  const unsigned short* ap2 = A + (size_t)(m0 + ar + 64) * K + as;

  const f32x4 zero4 = {0.f, 0.f, 0.f, 0.f};
  f32x4 acc[4][4];
#pragma unroll
  for (int i = 0; i < 4; ++i)
#pragma unroll
    for (int j = 0; j < 4; ++j) acc[i][j] = zero4;

  for (int k0 = 0; k0 < K; k0 += 32) {
    int4 va1 = *(const int4*)(ap1 + k0);
    int4 va2 = *(const int4*)(ap2 + k0);
    int4 vb1 = *(const int4*)(bp1 + k0);
    int4 vb2 = *(const int4*)(bp2 + k0);
    __syncthreads();
    *(int4*)&As[ar][as] = va1;
    *(int4*)&As[ar + 64][as] = va2;
    *(int4*)&Bs[ar][as] = vb1;
    *(int4*)&Bs[ar + 64][as] = vb2;
    __syncthreads();
    short8 af[4], bf[4];
#pragma unroll
    for (int i = 0; i < 4; ++i) af[i] = *(const short8*)&As[wm + i * 16 + lr][lk];
#pragma unroll
    for (int j = 0; j < 4; ++j) bf[j] = *(const short8*)&Bs[wn + j * 16 + lr][lk];
#pragma unroll
    for (int i = 0; i < 4; ++i)
#pragma unroll
      for (int j = 0; j < 4; ++j)
        acc[i][j] = __builtin_amdgcn_mfma_f32_16x16x32_f16(af[i], bf[j], acc[i][j], 0, 0, 0);
  }

#pragma unroll
  for (int j = 0; j < 4; ++j) {
    int col = n0 + wn + j * 16 + lr;
    int g = col >> gshift;
    const float* bp = (g == 0 ? b0 : (g == 1 ? b1 : b2));
    float bv = bp[col & kmask];
#pragma unroll
    for (int i = 0; i < 4; ++i) {
      int rbase = m0 + wm + i * 16 + (lane >> 4) * 4;
#pragma unroll
      for (int r = 0; r < 4; ++r) {
        int mrow = rbase + r;
        size_t off;
        if (permute) {
          int s = mrow >> 4, b = mrow & 15;
          off = ((size_t)(b * S_ + s)) * ldc + col;
        } else {
          off = (size_t)mrow * ldc + col;
        }
        C[off] = acc[i][j][r] + bv;
      }
    }
  }
}

// ---------------- tagged-packet comm primitives ----------------
// Packet (16B): { f16 d0..d3 (8B), u32 tag, u32 pad }. One dwordx4 store/load
// = atomically consistent tag+data. sc0 sc1 = LLC-coherent, no invalidations.

__device__ __forceinline__ void llc_store16(u32x4* p, u32x4 v) {
  asm volatile("global_store_dwordx4 %0, %1, off sc0 sc1" :: "v"(p), "v"(v) : "memory");
}

template<int KK>
__device__ __forceinline__ void spinT(const u32x4* __restrict__ base, unsigned tag,
                                      u32x4 (&ch)[KK][2]) {
  while (true) {
#pragma unroll
    for (int kk = 0; kk < KK; ++kk) {
      asm volatile("global_load_dwordx4 %0, %1, off sc0 sc1"
                   : "=v"(ch[kk][0]) : "v"(base + kk * 8));
      asm volatile("global_load_dwordx4 %0, %1, off sc0 sc1"
                   : "=v"(ch[kk][1]) : "v"(base + kk * 8 + 1));
    }
    asm volatile("s_waitcnt vmcnt(0)" ::: "memory");
    __builtin_amdgcn_sched_barrier(0);
    unsigned x = 0;
#pragma unroll
    for (int kk = 0; kk < KK; ++kk)
      x |= (ch[kk][0].z ^ tag) | (ch[kk][1].z ^ tag);
    if (__all(x == 0)) return;
    __builtin_amdgcn_s_sleep(2);
  }
}

// ---------------- fused 2-layer pipelined persistent GRU scan ----------------
// 128 blocks x 256 threads (4 waves). Blocks [0,64): layer 0; [64,128): layer 1.
// Block owns 16 features (j0 = fblk*16). Layer 0: wave w reduces k-quarter w*256
// (KK=8) of the h0 recurrence. Layer 1 fuses x-side: waves 0,1 reduce h1/rh1
// k-halves (KK=16) vs Wh1; waves 2,3 reduce h0(t) k-halves vs Wx1 (z,r,n).
// h0 travels through a depth-4 tagged ring; layer-1 progress array gives layer-0
// back-pressure (slack 3, never binds in steady state). Tags = t+1 (0 = initial
// zero state, so t=0 needs no special casing).
struct SMem {
  float combA[3][4][64][4];
  float combB[4][64][4];
  unsigned short stgr[16][16];
  unsigned short stgh[16][16];
};

template<int LAYER>
__device__ __forceinline__ void scan_body(
    SMem& sm,
    const float* __restrict__ Gx,
    const float* __restrict__ Whz, const float* __restrict__ Whr, const float* __restrict__ Whn,
    const unsigned short* __restrict__ Wxz, const unsigned short* __restrict__ Wxr,
    const unsigned short* __restrict__ Wxn,
    const float* __restrict__ bxz, const float* __restrict__ bxr, const float* __restrict__ bxn,
    unsigned short* __restrict__ Hs1,
    u32x4* __restrict__ hchk0, u32x4* __restrict__ rchk0,
    u32x4* __restrict__ hchk1, u32x4* __restrict__ rchk1,
    unsigned* __restrict__ prog,
    float* __restrict__ hfin, int fblk) {
  const int tid = threadIdx.x, lane = tid & 63, w = tid >> 6;
  const int j0 = fblk * 16;
  const int lj = lane & 15, lq = lane >> 4, bq = lq * 4;
  constexpr int KK = LAYER ? 16 : 8;
  const bool xw = (LAYER == 1) && (w >= 2);
  const int koff = LAYER ? ((w & 1) * 512) : (w * 256);

  // ---- weight preload: lane holds W[j0+lj][koff + kk*32 + lq*8 .. +8] ----
  short8 wz[KK], wr[KK], wn[KK];
  {
    const size_t row = (size_t)(j0 + lj) * H_;
    if (xw) {
#pragma unroll
      for (int kk = 0; kk < KK; ++kk) {
        int col = koff + kk * 32 + lq * 8;
        wz[kk] = *(const short8*)(Wxz + row + col);
        wr[kk] = *(const short8*)(Wxr + row + col);
        wn[kk] = *(const short8*)(Wxn + row + col);
      }
    } else {
#pragma unroll
      for (int kk = 0; kk < KK; ++kk) {
        int col = koff + kk * 32 + lq * 8;
        short8 a, b, c;
#pragma unroll
        for (int e = 0; e < 8; ++e) {
          a[e] = (short)f2h(Whz[row + col + e]);
          b[e] = (short)f2h(Whr[row + col + e]);
          c[e] = (short)f2h(Whn[row + col + e]);
        }
        wz[kk] = a; wr[kk] = b; wn[kk] = c;
      }
    }
  }
  float bz = 0.f, brr = 0.f, bnn = 0.f;
  if (LAYER == 1 && w == 0) { bz = bxz[j0 + lj]; brr = bxr[j0 + lj]; bnn = bxn[j0 + lj]; }

  const unsigned pkt = (unsigned)lj * 256u + (unsigned)(koff >> 2) + (unsigned)lq * 2u;
  u32x4* const myrch = LAYER ? rchk1 : rchk0;

  float hold[4] = {0.f, 0.f, 0.f, 0.f};
  float zv[4], gxn[4];
  const f32x4 z4 = {0.f, 0.f, 0.f, 0.f};

  for (int t = 0; t < S_; ++t) {
    float gz[4], gr[4], gn[4];
    if (LAYER == 0 && w == 0) {
      const float* gxt = Gx + (size_t)t * (B_ * 3 * H_) + j0 + lj;
#pragma unroll
      for (int r = 0; r < 4; ++r) {
        const float* gb = gxt + (size_t)(bq + r) * (3 * H_);
        gz[r] = gb[0]; gr[r] = gb[H_]; gn[r] = gb[2 * H_];
      }
    }

    // ---------- phase A ----------
    u32x4 ch[KK][2];
    {
      const u32x4* asrc; unsigned tagA;
      if (LAYER == 0) { asrc = hchk0 + ((unsigned)(t + 3) & 3u) * 4096u + pkt; tagA = (unsigned)t; }
      else if (!xw)   { asrc = hchk1 + pkt; tagA = (unsigned)t; }
      else            { asrc = hchk0 + ((unsigned)t & 3u) * 4096u + pkt; tagA = (unsigned)(t + 1); }
      spinT<KK>(asrc, tagA, ch);
    }
    f32x4 zacc = z4, racc = z4, nxacc = z4;
#pragma unroll
    for (int kk = 0; kk < KK; ++kk) {
      u32x4 fv = {ch[kk][0].x, ch[kk][0].y, ch[kk][1].x, ch[kk][1].y};
      short8 af = __builtin_bit_cast(short8, fv);
      zacc = __builtin_amdgcn_mfma_f32_16x16x32_f16(af, wz[kk], zacc, 0, 0, 0);
      racc = __builtin_amdgcn_mfma_f32_16x16x32_f16(af, wr[kk], racc, 0, 0, 0);
      if (xw) nxacc = __builtin_amdgcn_mfma_f32_16x16x32_f16(af, wn[kk], nxacc, 0, 0, 0);
    }
    if (w) {
      *(f32x4*)&sm.combA[0][w][lane][0] = zacc;
      *(f32x4*)&sm.combA[1][w][lane][0] = racc;
      if (xw) *(f32x4*)&sm.combA[2][w][lane][0] = nxacc;
    }
    __syncthreads();
    if (LAYER == 1 && tid == 0) {  // h0(t) consumed by all waves of this block
      unsigned pvv = (unsigned)(t + 1);
      asm volatile("global_store_dword %0, %1, off sc0 sc1"
                   :: "v"(prog + fblk * 32), "v"(pvv) : "memory");
    }
    if (w == 0) {
#pragma unroll
      for (int ww = 1; ww < 4; ++ww) {
        zacc += *(const f32x4*)&sm.combA[0][ww][lane][0];
        racc += *(const f32x4*)&sm.combA[1][ww][lane][0];
      }
      f32x4 nx = z4;
      if (LAYER == 1)
        nx = *(const f32x4*)&sm.combA[2][2][lane][0] + *(const f32x4*)&sm.combA[2][3][lane][0];
#pragma unroll
      for (int r = 0; r < 4; ++r) {
        float az = (LAYER ? bz : gz[r]) + zacc[r];
        float ar = (LAYER ? brr : gr[r]) + racc[r];
        gxn[r] = LAYER ? (bnn + nx[r]) : gn[r];
        zv[r] = 1.f / (1.f + __expf(-az));
        float rv = 1.f / (1.f + __expf(-ar));
        sm.stgr[bq + r][lj] = f2h(rv * hold[r]);
      }
      asm volatile("s_waitcnt lgkmcnt(0)" ::: "memory");
      {
        const int b = lane >> 2, cl = lane & 3;
        const unsigned* s = (const unsigned*)&sm.stgr[b][cl * 4];
        u32x4 pktv = {s[0], s[1], (unsigned)(t + 1), 0u};
        llc_store16(myrch + (unsigned)b * 256u + (unsigned)fblk * 4u + (unsigned)cl, pktv);
      }
    }

    // ---------- phase B ----------
    unsigned pv = 0;
    if (LAYER == 0 && w == 0)  // flow-control prefetch; spin's vmcnt(0) completes it
      asm volatile("global_load_dword %0, %1, off sc0 sc1"
                   : "=v"(pv) : "v"(prog + lane * 32));
    f32x4 nacc = z4;
    if (!xw) {
      spinT<KK>(myrch + pkt, (unsigned)(t + 1), ch);
#pragma unroll
      for (int kk = 0; kk < KK; ++kk) {
        u32x4 fv = {ch[kk][0].x, ch[kk][0].y, ch[kk][1].x, ch[kk][1].y};
        short8 af = __builtin_bit_cast(short8, fv);
        nacc = __builtin_amdgcn_mfma_f32_16x16x32_f16(af, wn[kk], nacc, 0, 0, 0);
      }
      if (w) *(f32x4*)&sm.combB[w][lane][0] = nacc;
    }
    __syncthreads();
    if (w == 0) {
#pragma unroll
      for (int ww = 1; ww <= (LAYER ? 1 : 3); ++ww)
        nacc += *(const f32x4*)&sm.combB[ww][lane][0];
#pragma unroll
      for (int r = 0; r < 4; ++r) {
        float nv = tanhf(gxn[r] + nacc[r]);
        float hn = (1.f - zv[r]) * nv + zv[r] * hold[r];
        hold[r] = hn;
        sm.stgh[bq + r][lj] = f2h(hn);
        if (t == S_ - 1) hfin[(size_t)(bq + r) * H_ + j0 + lj] = hn;
      }
      asm volatile("s_waitcnt lgkmcnt(0)" ::: "memory");
      if (LAYER == 0) {  // ring overwrite guard: all layer-1 blocks past h0(t-4)
        int need = t - 3;
        asm volatile("s_waitcnt vmcnt(0)" ::: "memory");
        while (__any((int)pv < need)) {
          __builtin_amdgcn_s_sleep(8);
          asm volatile("global_load_dword %0, %1, off sc0 sc1"
                       : "=v"(pv) : "v"(prog + lane * 32));
          asm volatile("s_waitcnt vmcnt(0)" ::: "memory");
        }
      }
      {
        const int b = lane >> 2, cl = lane & 3;
        const unsigned* s = (const unsigned*)&sm.stgh[b][cl * 4];
        u32x4 pktv = {s[0], s[1], (unsigned)(t + 1), 0u};
        u32x4* dst = LAYER
            ? (hchk1 + (unsigned)b * 256u + (unsigned)fblk * 4u + (unsigned)cl)
            : (hchk0 + ((unsigned)t & 3u) * 4096u + (unsigned)b * 256u + (unsigned)fblk * 4u + (unsigned)cl);
        llc_store16(dst, pktv);
        if (LAYER == 1) {
          unsigned long long dv = (unsigned long long)s[0] | ((unsigned long long)s[1] << 32);
          *(unsigned long long*)(Hs1 + ((size_t)t * B_ + b) * H_ + j0 + cl * 4) = dv;
        }
      }
    }
  }
}

__global__ __launch_bounds__(256, 1) void k_scan2(
    const float* __restrict__ Gx,
    const float* __restrict__ Whz0, const float* __restrict__ Whr0, const float* __restrict__ Whn0,
    const float* __restrict__ Whz1, const float* __restrict__ Whr1, const float* __restrict__ Whn1,
    const unsigned short* __restrict__ Wxz1, const unsigned short* __restrict__ Wxr1,
    const unsigned short* __restrict__ Wxn1,
    const float* __restrict__ bxz1, const float* __restrict__ bxr1, const float* __restrict__ bxn1,
    unsigned short* __restrict__ Hs1,
    u32x4* __restrict__ hchk0, u32x4* __restrict__ rchk0,
    u32x4* __restrict__ hchk1, u32x4* __restrict__ rchk1,
    unsigned* __restrict__ prog, float* __restrict__ h0f, float* __restrict__ h1f) {
  __shared__ SMem sm;
  if (blockIdx.x < 64)
    scan_body<0>(sm, Gx, Whz0, Whr0, Whn0, nullptr, nullptr, nullptr,
                 nullptr, nullptr, nullptr, nullptr,
                 hchk0, rchk0, hchk1, rchk1, prog, h0f, blockIdx.x);
  else
    scan_body<1>(sm, nullptr, Whz1, Whr1, Whn1, Wxz1, Wxr1, Wxn1,
                 bxz1, bxr1, bxn1, Hs1,
                 hchk0, rchk0, hchk1, rchk1, prog, h1f, blockIdx.x - 64);
}

// ---------------- host ----------------

extern "C" void kernel_launch(void* const* d_in, const int* in_sizes, int n_in,
                              void* d_out, int out_size, void* d_ws, size_t ws_size,
                              hipStream_t stream) {
  const int*   x    = (const int*)d_in[0];
  const float* emb  = (const float*)d_in[1];
  const float* wxz0 = (const float*)d_in[2];
  const float* bxz0 = (const float*)d_in[3];
  const float* whz0 = (const float*)d_in[4];
  const float* wxr0 = (const float*)d_in[5];
  const float* bxr0 = (const float*)d_in[6];
  const float* whr0 = (const float*)d_in[7];
  const float* wxn0 = (const float*)d_in[8];
  const float* bxn0 = (const float*)d_in[9];
  const float* whn0 = (const float*)d_in[10];
  const float* wxz1 = (const float*)d_in[11];
  const float* bxz1 = (const float*)d_in[12];
  const float* whz1 = (const float*)d_in[13];
  const float* wxr1 = (const float*)d_in[14];
  const float* bxr1 = (const float*)d_in[15];
  const float* whr1 = (const float*)d_in[16];
  const float* wxn1 = (const float*)d_in[17];
  const float* bxn1 = (const float*)d_in[18];
  const float* whn1 = (const float*)d_in[19];
  const float* fcw  = (const float*)d_in[20];
  const float* fcb  = (const float*)d_in[21];
  float* out = (float*)d_out;

  char* w = (char*)d_ws;
  size_t off = 0;
  auto alloc = [&](size_t bytes) {
    void* p = w + off;
    off += (bytes + 255) & ~(size_t)255;
    return p;
  };
  unsigned short* xe   = (unsigned short*)alloc((size_t)4096 * E_ * 2);
  unsigned short* wz0b = (unsigned short*)alloc((size_t)H_ * E_ * 2);
  unsigned short* wr0b = (unsigned short*)alloc((size_t)H_ * E_ * 2);
  unsigned short* wn0b = (unsigned short*)alloc((size_t)H_ * E_ * 2);
  unsigned short* wz1b = (unsigned short*)alloc((size_t)H_ * H_ * 2);
  unsigned short* wr1b = (unsigned short*)alloc((size_t)H_ * H_ * 2);
  unsigned short* wn1b = (unsigned short*)alloc((size_t)H_ * H_ * 2);
  unsigned short* fcwb = (unsigned short*)alloc((size_t)V_ * H_ * 2);
  float* Gx = (float*)alloc((size_t)4096 * 3 * H_ * 4);
  unsigned short* Hs1 = (unsigned short*)alloc((size_t)4096 * H_ * 2);
  // tagged-packet region (contiguous, zeroed every launch):
  u32x4* hchk0 = (u32x4*)alloc((size_t)4 * 4096 * 16);  // depth-4 ring
  u32x4* rchk0 = (u32x4*)alloc((size_t)4096 * 16);
  u32x4* hchk1 = (u32x4*)alloc((size_t)4096 * 16);
  u32x4* rchk1 = (u32x4*)alloc((size_t)4096 * 16);
  unsigned* prog = (unsigned*)alloc((size_t)64 * 32 * 4);
  size_t zbytes = ((char*)prog + 64 * 32 * 4) - (char*)hchk0;

  float* h0f = out + (size_t)B_ * S_ * V_;
  float* h1f = h0f + (size_t)B_ * H_;

  // zero packet buffers + progress (kills stale tags incl. graph replays)
  {
    int nz = (int)(zbytes / 4);
    k_init<<<(nz + 255) / 256, 256, 0, stream>>>((unsigned*)hchk0, nz);
  }

  // prep: gather + casts (f16)
  k_gather<<<4096, 128, 0, stream>>>(x, emb, xe);
  k_cast<<<(H_ * E_ / 4 + 255) / 256, 256, 0, stream>>>(wxz0, wz0b, H_ * E_ / 4);
  k_cast<<<(H_ * E_ / 4 + 255) / 256, 256, 0, stream>>>(wxr0, wr0b, H_ * E_ / 4);
  k_cast<<<(H_ * E_ / 4 + 255) / 256, 256, 0, stream>>>(wxn0, wn0b, H_ * E_ / 4);
  k_cast<<<(H_ * H_ / 4 + 255) / 256, 256, 0, stream>>>(wxz1, wz1b, H_ * H_ / 4);
  k_cast<<<(H_ * H_ / 4 + 255) / 256, 256, 0, stream>>>(wxr1, wr1b, H_ * H_ / 4);
  k_cast<<<(H_ * H_ / 4 + 255) / 256, 256, 0, stream>>>(wxn1, wn1b, H_ * H_ / 4);
  k_cast<<<(V_ * H_ / 4 + 255) / 256, 256, 0, stream>>>(fcw, fcwb, V_ * H_ / 4);

  // Gx0 = xe @ Wx0^T + b  (M=4096, N=3072, K=512) — layer-0 x-side only
  k_gemm<<<32 * 24, 256, 0, stream>>>(xe, wz0b, wr0b, wn0b, bxz0, bxr0, bxn0,
                                      Gx, E_, 32, 10, 0, 3 * H_);
  // fused pipelined 2-layer scan
  k_scan2<<<128, 256, 0, stream>>>(Gx, whz0, whr0, whn0, whz1, whr1, whn1,
                                   wz1b, wr1b, wn1b, bxz1, bxr1, bxn1, Hs1,
                                   hchk0, rchk0, hchk1, rchk1, prog, h0f, h1f);
  // out = Hs1 @ fcw^T + fcb  (M=4096, N=32000, K=1024), permuted to [B][S][V]
  k_gemm<<<32 * 250, 256, 0, stream>>>(Hs1, fcwb, fcwb, fcwb, fcb, fcb, fcb,
                                       out, H_, 32, 30, 1, V_);

  (void)in_sizes; (void)n_in; (void)out_size; (void)ws_size;
}